// Round 9
// baseline (1882.554 us; speedup 1.0000x reference)
//
#include <hip/hip_runtime.h>

#define B_ 8
#define C_ 256
#define H_ 64
#define W_ 64
#define HW_ 4096
#define A_ 9
#define SITES 36864      // A_*HW_
#define NPOST 1000
#define XCLIPF 4.1351666f   // (float)4.135166556742356
#define IMGF 1024.0f
#define PROW 68             // padded row width (floats), 16B-multiple
#define PCH  (65 * PROW)    // padded channel stride (65 rows: 1 zero + 64 data)
#define PB_  ((256 * 65 + 1) * PROW)  // floats per padded batch = 1,131,588

__device__ inline unsigned keyf(float v) {
  unsigned u = __float_as_uint(v);
  return (u & 0x80000000u) ? ~u : (u | 0x80000000u);  // ascending uint == ascending float
}

// ---------------- K0: prepad x into zero-haloed layout ----------------
// Batch layout: rows 0..16640 of 68 floats. Row R: R%65==0 -> all zero (vertical halo,
// shared between adjacent channels); else channel ci=R/65, data row r=R%65-1 at cols 1..64;
// cols 0 and 65..67 zero (horizontal halo + alignment pad).
__global__ __launch_bounds__(256) void prepad(
    const float* __restrict__ x, float* __restrict__ xpad, int total) {
  int idx = blockIdx.x * 256 + threadIdx.x;
  if (idx >= total) return;
  int b = idx / PB_;
  int rem = idx - b * PB_;
  int R = rem / PROW;
  int col = rem - R * PROW;
  int rr = R % 65;
  float v = 0.f;
  if (rr != 0 && col >= 1 && col <= 64) {
    int ci = R / 65;
    v = x[(size_t)b * C_ * HW_ + (size_t)ci * HW_ + (size_t)(rr - 1) * W_ + (col - 1)];
  }
  xpad[idx] = v;
}

// ---------------- K1: 3x3 conv + bias + relu, bit-exact f32, pure-load from padded buf ----------------
// Exact op order preserved (identical chains to rounds 4-8, absmax 0.0): per pixel,
// 9 independent fmaf chains over ci ascending; tap-ordered left-assoc sum; +bias; relu.
// Zero-pad taps are the same exact fmaf(w,0,acc) no-ops as the validated kernels.
// grid: B_*C_*2 blocks; 256 threads = 32 rows x 8 chunks; 8 px/thread.
// 9 loads/ci off ONE address register (imm offsets), 1 pointer bump; no shfl, no cndmask.
__global__ __launch_bounds__(256, 4) void conv3_pad(
    const float* __restrict__ xpad, const float* __restrict__ w,
    const float* __restrict__ bias, float* __restrict__ feats) {
#pragma clang fp contract(off)
  int b    = blockIdx.x >> 9;
  int co   = (blockIdx.x >> 1) & 255;
  int half = blockIdx.x & 1;
  int gr   = (half << 5) + (threadIdx.x >> 3);   // output row 0..63
  int c0   = (threadIdx.x & 7) << 3;             // buffer window start (=16B aligned)
  // top halo row of output row gr for channel ci sits at buffer row ci*65 + gr
  const float* q = xpad + (size_t)b * PB_ + (size_t)gr * PROW + c0;
  const float* wp = w + (size_t)co * (C_ * 9);

  float acc[8][9];
#pragma unroll
  for (int p = 0; p < 8; ++p)
#pragma unroll
    for (int t = 0; t < 9; ++t) acc[p][t] = 0.f;

  for (int ci = 0; ci < C_; ++ci) {
    float4 tA = *(const float4*)(q);
    float4 tB = *(const float4*)(q + 4);
    float2 tC = *(const float2*)(q + 8);
    float4 mA = *(const float4*)(q + PROW);
    float4 mB = *(const float4*)(q + PROW + 4);
    float2 mC = *(const float2*)(q + PROW + 8);
    float4 bA = *(const float4*)(q + 2 * PROW);
    float4 bB = *(const float4*)(q + 2 * PROW + 4);
    float2 bC = *(const float2*)(q + 2 * PROW + 8);
    q += PCH;

    float T[10]  = {tA.x, tA.y, tA.z, tA.w, tB.x, tB.y, tB.z, tB.w, tC.x, tC.y};
    float M[10]  = {mA.x, mA.y, mA.z, mA.w, mB.x, mB.y, mB.z, mB.w, mC.x, mC.y};
    float Bo[10] = {bA.x, bA.y, bA.z, bA.w, bB.x, bB.y, bB.z, bB.w, bC.x, bC.y};

    float w9[9];
#pragma unroll
    for (int t = 0; t < 9; ++t) w9[t] = wp[ci * 9 + t];   // wave-uniform -> s_load

#pragma unroll
    for (int p = 0; p < 8; ++p) {
      acc[p][0] = fmaf(w9[0], T[p],     acc[p][0]);
      acc[p][1] = fmaf(w9[1], T[p+1],   acc[p][1]);
      acc[p][2] = fmaf(w9[2], T[p+2],   acc[p][2]);
      acc[p][3] = fmaf(w9[3], M[p],     acc[p][3]);
      acc[p][4] = fmaf(w9[4], M[p+1],   acc[p][4]);
      acc[p][5] = fmaf(w9[5], M[p+2],   acc[p][5]);
      acc[p][6] = fmaf(w9[6], Bo[p],    acc[p][6]);
      acc[p][7] = fmaf(w9[7], Bo[p+1],  acc[p][7]);
      acc[p][8] = fmaf(w9[8], Bo[p+2],  acc[p][8]);
    }
  }

  float bv = bias[co];
  float ov[8];
#pragma unroll
  for (int p = 0; p < 8; ++p) {
    float a = 0.f;
#pragma unroll
    for (int t = 0; t < 9; ++t) a = a + acc[p][t];  // tap-ordered, left-assoc
    a = a + bv;
    ov[p] = a > 0.f ? a : 0.f;
  }
  float4* fo = (float4*)(feats + ((size_t)b * C_ + co) * HW_ + (size_t)gr * W_ + c0);
  fo[0] = make_float4(ov[0], ov[1], ov[2], ov[3]);
  fo[1] = make_float4(ov[4], ov[5], ov[6], ov[7]);
}

// ---------------- K2: fused 1x1 convs (36 box + 9 obj), bit-exact f32 chains ----------------
__global__ __launch_bounds__(256) void conv1_fused(
    const float* __restrict__ feats,
    const float* __restrict__ box_w, const float* __restrict__ box_b,
    const float* __restrict__ obj_w, const float* __restrict__ obj_b,
    float* __restrict__ tbox, float* __restrict__ scores) {
#pragma clang fp contract(off)
  int idx = blockIdx.x * 256 + threadIdx.x;
  int b = idx >> 12;
  int hw = idx & 4095;
  const float* f = feats + (size_t)b * C_ * HW_ + hw;
  float acc[45];
#pragma unroll
  for (int c = 0; c < 45; ++c) acc[c] = 0.f;
  for (int ci = 0; ci < C_; ++ci) {
    float fv = f[(size_t)ci * HW_];
#pragma unroll
    for (int c = 0; c < 36; ++c)
      acc[c] = fmaf(box_w[c * C_ + ci], fv, acc[c]);
#pragma unroll
    for (int a = 0; a < 9; ++a)
      acc[36 + a] = fmaf(obj_w[a * C_ + ci], fv, acc[36 + a]);
  }
#pragma unroll
  for (int c = 0; c < 36; ++c) {
    int k = c / 9, a = c - k * 9;
    tbox[(size_t)b * 4 * SITES + (size_t)k * SITES + (size_t)a * HW_ + hw] = acc[c] + box_b[c];
  }
#pragma unroll
  for (int a = 0; a < 9; ++a)
    scores[(size_t)b * SITES + (size_t)a * HW_ + hw] = acc[36 + a] + obj_b[a];
}

// ---------------- K3: exact radix-select of the 1000th-smallest key per batch ----------------
__global__ __launch_bounds__(1024) void radix_select(
    const float* __restrict__ scores, unsigned* __restrict__ Kout,
    int* __restrict__ needEq, int* __restrict__ cnt, int* __restrict__ eqCnt) {
  int b = blockIdx.x;
  const float* s = scores + (size_t)b * SITES;
  __shared__ unsigned hist[256];
  __shared__ unsigned sh_prefix, sh_mask, sh_cless;
  __shared__ int sh_target;
  if (threadIdx.x == 0) { sh_prefix = 0; sh_mask = 0; sh_target = NPOST - 1; sh_cless = 0; }
  for (int shift = 24; shift >= 0; shift -= 8) {
    if (threadIdx.x < 256) hist[threadIdx.x] = 0;
    __syncthreads();
    unsigned prefix = sh_prefix, mask = sh_mask;
    for (int i = threadIdx.x; i < SITES; i += 1024) {
      unsigned k = keyf(s[i]);
      if ((k & mask) == prefix) atomicAdd(&hist[(k >> shift) & 255u], 1u);
    }
    __syncthreads();
    if (threadIdx.x == 0) {
      unsigned cum = 0; int t = sh_target; int v = 0;
      for (; v < 256; ++v) {
        unsigned h = hist[v];
        if (cum + h > (unsigned)t) break;
        cum += h;
      }
      sh_prefix |= ((unsigned)v) << shift;
      sh_mask   |= 0xFFu << shift;
      sh_target  = t - (int)cum;
      sh_cless  += cum;
    }
    __syncthreads();
  }
  if (threadIdx.x == 0) {
    Kout[b] = sh_prefix;
    needEq[b] = NPOST - (int)sh_cless;
    cnt[b] = 0;
    eqCnt[b] = 0;
  }
}

// ---------------- K4: compact k<K sites; collect k==K sites ----------------
__global__ __launch_bounds__(256) void compact_sel(
    const float* __restrict__ scores, const unsigned* __restrict__ Kout,
    int* __restrict__ cnt, int* __restrict__ sel,
    int* __restrict__ eqCnt, int* __restrict__ eqList) {
  int b = blockIdx.x / 144;
  int i = (blockIdx.x % 144) * 256 + threadIdx.x;
  unsigned K = Kout[b];
  unsigned k = keyf(scores[(size_t)b * SITES + i]);
  if (k < K) {
    int pos = atomicAdd(&cnt[b], 1);
    sel[b * 1024 + pos] = i;               // arbitrary order: order_decode re-sorts
  } else if (k == K) {
    int e = atomicAdd(&eqCnt[b], 1);
    if (e < 4096) eqList[b * 4096 + e] = i;
  }
}

// ---------------- K4b: take the needEq smallest-index equal-key sites ----------------
__global__ __launch_bounds__(256) void fix_eq(
    const int* __restrict__ cnt, const int* __restrict__ needEq,
    const int* __restrict__ eqCnt, const int* __restrict__ eqList,
    int* __restrict__ sel) {
  int b = blockIdx.x;
  int E = eqCnt[b]; if (E > 4096) E = 4096;
  int need = needEq[b];
  int base = cnt[b];
  const int* el = eqList + b * 4096;
  for (int t = threadIdx.x; t < E; t += 256) {
    int site = el[t];
    int rank = 0;
    for (int q = 0; q < E; ++q) rank += (el[q] < site);
    if (rank < need) sel[b * 1024 + base + rank] = site;
  }
}

// ---------------- K5: descending order of the selected 1000 + fused decode ----------------
__global__ __launch_bounds__(1024) void order_decode(
    const float* __restrict__ scores, const int* __restrict__ sel,
    const float* __restrict__ tbox, float* __restrict__ s2, float* __restrict__ b2) {
#pragma clang fp contract(off)
  int b = blockIdx.x;
  int r = threadIdx.x;
  __shared__ float ss[NPOST];
  __shared__ int st[NPOST];
  if (r < NPOST) {
    int site = sel[b * 1024 + r];
    st[r] = site;
    ss[r] = scores[(size_t)b * SITES + site];
  }
  __syncthreads();
  if (r < NPOST) {
    float sr = ss[r]; int sir = st[r];
    int d = 0;
    for (int q = 0; q < NPOST; ++q) {
      float sq = ss[q];
      d += (int)((sq > sr) || (sq == sr && st[q] < sir));
    }
    s2[(size_t)b * NPOST + d] = sr;
    int site = sir;
    int a = site / HW_;
    int hw = site - a * HW_;
    int h = hw / W_, wc = hw - h * W_;
    int sidx = a / 3, ridx = a - sidx * 3;
    float scale = (sidx == 0) ? 128.f : ((sidx == 1) ? 256.f : 512.f);
    float ratio = (ridx == 0) ? 0.5f : ((ridx == 1) ? 1.0f : 2.0f);
    float sq = sqrtf(ratio);
    float wsa = scale / sq;
    float hsa = scale * sq;
    float cx = ((float)wc + 0.5f) * 16.f;
    float cy = ((float)h + 0.5f) * 16.f;
    float ax1 = cx - wsa * 0.5f;
    float ay1 = cy - hsa * 0.5f;
    float ax2 = cx + wsa * 0.5f;
    float ay2 = cy + hsa * 0.5f;
    float aw = ax2 - ax1, ah = ay2 - ay1;
    float m1 = 0.5f * aw, m2 = 0.5f * ah;
    float acx = ax1 + m1, acy = ay1 + m2;
    const float* tb = tbox + (size_t)b * 4 * SITES + site;
    float t0 = tb[0];
    float t1 = tb[SITES];
    float t2 = tb[2 * (size_t)SITES];
    float t3 = tb[3 * (size_t)SITES];
    if (t2 < -XCLIPF) t2 = -XCLIPF;
    if (t2 > XCLIPF) t2 = XCLIPF;
    if (t3 < -XCLIPF) t3 = -XCLIPF;
    if (t3 > XCLIPF) t3 = XCLIPF;
    float pm0 = t0 * aw;  float pcx = pm0 + acx;
    float pm1 = t1 * ah;  float pcy = pm1 + acy;
    float pw = expf(t2) * aw;
    float ph = expf(t3) * ah;
    float hw0 = 0.5f * pw, hh0 = 0.5f * ph;
    float x1 = pcx - hw0, y1 = pcy - hh0;
    float x2 = pcx + hw0, y2 = pcy + hh0;
    x1 = x1 < 0.f ? 0.f : (x1 > IMGF ? IMGF : x1);
    y1 = y1 < 0.f ? 0.f : (y1 > IMGF ? IMGF : y1);
    x2 = x2 < 0.f ? 0.f : (x2 > IMGF ? IMGF : x2);
    y2 = y2 < 0.f ? 0.f : (y2 > IMGF ? IMGF : y2);
    float* o = b2 + ((size_t)b * NPOST + d) * 4;
    o[0] = x1; o[1] = y1; o[2] = x2; o[3] = y2;
  }
}

// ---------------- K6a: suppression bitmask (j > i && IoU > 0.7), f32, exact op order ----------------
__global__ __launch_bounds__(256) void mask_kernel(
    const float* __restrict__ b2, unsigned long long* __restrict__ sup) {
#pragma clang fp contract(off)
  int b = blockIdx.x / 63;
  int i0 = (blockIdx.x % 63) * 16;
  __shared__ float bs[NPOST * 4];
  __shared__ float area[NPOST];
  for (int t = threadIdx.x; t < NPOST * 4; t += 256) bs[t] = b2[(size_t)b * NPOST * 4 + t];
  __syncthreads();
  for (int t = threadIdx.x; t < NPOST; t += 256)
    area[t] = (bs[t * 4 + 2] - bs[t * 4]) * (bs[t * 4 + 3] - bs[t * 4 + 1]);
  __syncthreads();
  int i = i0 + (threadIdx.x >> 4);
  int wd = threadIdx.x & 15;
  if (i >= NPOST) return;
  float ax1 = bs[i * 4], ay1 = bs[i * 4 + 1], ax2 = bs[i * 4 + 2], ay2 = bs[i * 4 + 3];
  float aa = area[i];
  unsigned long long m = 0;
  for (int bit = 0; bit < 64; ++bit) {
    int j = wd * 64 + bit;
    if (j > i && j < NPOST) {
      float lx = fmaxf(ax1, bs[j * 4]);
      float ly = fmaxf(ay1, bs[j * 4 + 1]);
      float rx = fminf(ax2, bs[j * 4 + 2]);
      float ry = fminf(ay2, bs[j * 4 + 3]);
      float iw = rx - lx; if (iw < 0.f) iw = 0.f;
      float ih = ry - ly; if (ih < 0.f) ih = 0.f;
      float inter = iw * ih;
      float denom = (aa + area[j]) - inter;
      float iou = inter / denom;
      if (iou > 0.7f) m |= 1ull << bit;
    }
  }
  sup[((size_t)b * NPOST + i) * 16 + wd] = m;
}

// ---------------- K6b: wave-synchronous NMS scan + compaction + zero fill ----------------
__global__ __launch_bounds__(64) void nms_out(
    const unsigned long long* __restrict__ sup, const float* __restrict__ b2,
    const float* __restrict__ s2, float* __restrict__ out) {
  int b = blockIdx.x;
  int lane = threadIdx.x;
  unsigned long long kw = 0;
  if (lane < 16) kw = (lane < 15) ? ~0ull : ((1ull << 40) - 1);  // bits 960..999 valid
  const unsigned long long* ms = sup + (size_t)b * NPOST * 16;
  unsigned long long m_cur = (lane < 16) ? ms[lane] : 0ull;
  for (int i = 0; i < NPOST; ++i) {
    unsigned long long m_nxt = (i + 1 < NPOST && lane < 16) ? ms[(size_t)(i + 1) * 16 + lane] : 0ull;
    unsigned long long w = __shfl(kw, i >> 6, 64);
    if ((w >> (i & 63)) & 1ull) {
      if (lane < 16) kw &= ~m_cur;
    }
    m_cur = m_nxt;
  }
  __shared__ unsigned long long keeps[16];
  if (lane < 16) keeps[lane] = kw;
  __syncthreads();
  int total = 0;
#pragma unroll
  for (int k = 0; k < 16; ++k) total += __popcll(keeps[k]);
  for (int i = lane; i < NPOST; i += 64) {
    int w = i >> 6;
    int before = 0;
    for (int k = 0; k < w; ++k) before += __popcll(keeps[k]);
    before += __popcll(keeps[w] & ((1ull << (i & 63)) - 1));
    bool kept = (keeps[w] >> (i & 63)) & 1ull;
    if (kept) {
      size_t ob = (size_t)b * (NPOST * 5) + (size_t)before * 5;
      const float* src = b2 + ((size_t)b * NPOST + i) * 4;
      out[ob + 0] = src[0];
      out[ob + 1] = src[1];
      out[ob + 2] = src[2];
      out[ob + 3] = src[3];
      out[ob + 4] = s2[(size_t)b * NPOST + i];
    }
    if (i >= total) {
      size_t ob = (size_t)b * (NPOST * 5) + (size_t)i * 5;
      for (int c = 0; c < 5; ++c) out[ob + c] = 0.f;
    }
  }
}

extern "C" void kernel_launch(void* const* d_in, const int* in_sizes, int n_in,
                              void* d_out, int out_size, void* d_ws, size_t ws_size,
                              hipStream_t stream) {
  const float *x = nullptr, *conv_w = nullptr, *conv_b = nullptr,
              *box_w = nullptr, *box_b = nullptr, *obj_w = nullptr, *obj_b = nullptr;
  for (int i = 0; i < n_in; ++i) {
    switch (in_sizes[i]) {
      case 8388608: x = (const float*)d_in[i]; break;
      case 589824:  conv_w = (const float*)d_in[i]; break;
      case 256:     conv_b = (const float*)d_in[i]; break;
      case 9216:    box_w = (const float*)d_in[i]; break;
      case 36:      box_b = (const float*)d_in[i]; break;
      case 2304:    obj_w = (const float*)d_in[i]; break;
      case 9:       obj_b = (const float*)d_in[i]; break;
    }
  }
  float* out = (float*)d_out;

  char* p = (char*)d_ws;
  auto alloc = [&](size_t n) { char* q = p; p += (n + 255) & ~255ull; return (void*)q; };
  float* xpad   = (float*)alloc((size_t)B_ * PB_ * 4);            // 36.21 MB
  float* feats  = (float*)alloc((size_t)B_ * C_ * HW_ * 4);       // 33.55 MB
  float* tbox   = (float*)alloc((size_t)B_ * 4 * SITES * 4);      // 4.72 MB
  float* scores = (float*)alloc((size_t)B_ * SITES * 4);          // 1.18 MB
  unsigned* Kout = (unsigned*)alloc(B_ * 4);
  int* needEq    = (int*)alloc(B_ * 4);
  int* cnt       = (int*)alloc(B_ * 4);
  int* eqCnt     = (int*)alloc(B_ * 4);
  int* eqList    = (int*)alloc((size_t)B_ * 4096 * 4);
  int* sel       = (int*)alloc((size_t)B_ * 1024 * 4);
  float* s2      = (float*)alloc((size_t)B_ * NPOST * 4);
  float* b2      = (float*)alloc((size_t)B_ * NPOST * 4 * 4);
  unsigned long long* sup = (unsigned long long*)alloc((size_t)B_ * NPOST * 16 * 8); // 1.02 MB

  int prepad_total = B_ * PB_;
  hipLaunchKernelGGL(prepad, dim3((prepad_total + 255) / 256), dim3(256), 0, stream,
                     x, xpad, prepad_total);
  hipLaunchKernelGGL(conv3_pad, dim3(B_ * C_ * 2), dim3(256), 0, stream,
                     xpad, conv_w, conv_b, feats);
  hipLaunchKernelGGL(conv1_fused, dim3(B_ * HW_ / 256), dim3(256), 0, stream,
                     feats, box_w, box_b, obj_w, obj_b, tbox, scores);
  hipLaunchKernelGGL(radix_select, dim3(B_), dim3(1024), 0, stream,
                     scores, Kout, needEq, cnt, eqCnt);
  hipLaunchKernelGGL(compact_sel, dim3(B_ * 144), dim3(256), 0, stream,
                     scores, Kout, cnt, sel, eqCnt, eqList);
  hipLaunchKernelGGL(fix_eq, dim3(B_), dim3(256), 0, stream,
                     cnt, needEq, eqCnt, eqList, sel);
  hipLaunchKernelGGL(order_decode, dim3(B_), dim3(1024), 0, stream,
                     scores, sel, tbox, s2, b2);
  hipLaunchKernelGGL(mask_kernel, dim3(B_ * 63), dim3(256), 0, stream, b2, sup);
  hipLaunchKernelGGL(nms_out, dim3(B_), dim3(64), 0, stream, sup, b2, s2, out);
}